// Round 14
// baseline (179.626 us; speedup 1.0000x reference)
//
#include <hip/hip_runtime.h>
#include <math.h>

typedef unsigned short u16;
typedef unsigned int u32;
typedef __bf16 bfrag8 __attribute__((ext_vector_type(8)));
typedef float f32x4 __attribute__((ext_vector_type(4)));

#define B_ 2
#define T_ 2048
#define H_ 16
#define D_ 64
#define C_ 1024
#define NQKV_ 3072

#define MFMA_BF16(a, b, c) __builtin_amdgcn_mfma_f32_16x16x32_bf16((a), (b), (c), 0, 0, 0)

__device__ __forceinline__ u16 f2bf(float f) {
  u32 u = __builtin_bit_cast(u32, f);
  u += 0x7fffu + ((u >> 16) & 1u);  // RNE
  return (u16)(u >> 16);
}

// exp2 via the target builtin: single v_exp_f32 with compiler-managed TRANS hazard
__device__ __forceinline__ float exp2_fast(float x) {
#if __has_builtin(__builtin_amdgcn_exp2f)
  return __builtin_amdgcn_exp2f(x);
#else
  return __expf(x * 0.6931471805599453f);
#endif
}

// async global->LDS, 16B/lane; lds dest = wave-uniform base + lane*16
__device__ __forceinline__ void load_lds16(const u16* gp, u16* lp) {
  __builtin_amdgcn_global_load_lds(
      (const __attribute__((address_space(1))) u32*)(const void*)gp,
      (__attribute__((address_space(3))) u32*)(void*)lp, 16, 0, 0);
}

// -------- fused prep: convert x (f32->bf16) + transpose both weights. --------
__global__ __launch_bounds__(256) void prep(const float* __restrict__ x,
                                            u16* __restrict__ xb,
                                            const float* __restrict__ wqkv,
                                            u16* __restrict__ wqkvT,
                                            const float* __restrict__ wproj,
                                            u16* __restrict__ wprojT) {
  int bid = blockIdx.x;
  int tid = threadIdx.x;
  __shared__ u16 tile[64][65];
  if (bid < 2048) {
    size_t i = ((size_t)bid * 256 + tid) * 8;
    const float* s = x + i;
    float4 a = *(const float4*)s, b = *(const float4*)(s + 4);
    union { uint4 v; u16 h[8]; } t;
    t.h[0] = f2bf(a.x); t.h[1] = f2bf(a.y); t.h[2] = f2bf(a.z); t.h[3] = f2bf(a.w);
    t.h[4] = f2bf(b.x); t.h[5] = f2bf(b.y); t.h[6] = f2bf(b.z); t.h[7] = f2bf(b.w);
    *(uint4*)(xb + i) = t.v;
    return;
  }
  const float* src;
  u16* dst;
  int N, bx, by;
  if (bid < 2816) {
    int rel = bid - 2048;
    src = wqkv; dst = wqkvT; N = NQKV_;
    bx = (rel % 48) * 64; by = (rel / 48) * 64;
  } else {
    int rel = bid - 2816;
    src = wproj; dst = wprojT; N = C_;
    bx = (rel & 15) * 64; by = (rel >> 4) * 64;
  }
  for (int idx = tid; idx < 4096; idx += 256) {
    int r = idx >> 6, c = idx & 63;
    tile[r][c] = f2bf(src[(size_t)(by + r) * N + bx + c]);
  }
  __syncthreads();
  for (int idx = tid; idx < 4096; idx += 256) {
    int r = idx >> 6, c = idx & 63;
    dst[(size_t)(bx + r) * C_ + by + c] = tile[c][r];
  }
}

// -------- GEMM 1: qkv = X(4096x1024)bf16 @ WT(3072x1024)bf16, RoPE epilogue.
// 128x128 tile, BK=64, dbuf chunk-XOR-swizzled LDS (r5-proven 45.5us, conflicts=0).
// REVERTED from r13's 128x192/384-thread retile (52.3us: runtime-bounded staging
// loop + wave imbalance ate more than the tail round cost). FROZEN — 4 structural
// rewrites (8-phase, depth-2 vmcnt, B-direct, 192-tile) all lost to this form.
// q pre-scaled by 0.125*log2e: attn computes P = exp2(S) directly. --------
__global__ __launch_bounds__(256) void gemm_qkv_rope(const u16* __restrict__ X,
                                                     const u16* __restrict__ WT,
                                                     u16* __restrict__ qb,
                                                     u16* __restrict__ kb,
                                                     u16* __restrict__ vtb) {
  const int K = C_;
  __shared__ __align__(16) u16 As[2][128 * 64];  // 32 KB
  __shared__ __align__(16) u16 Bs[2][128 * 64];  // 32 KB
  int tid = threadIdx.x;
  int lane = tid & 63, wave = tid >> 6;
  int quad = lane >> 4, lr = lane & 15;
  int m0 = blockIdx.y * 128, n0 = blockIdx.x * 128;
  int wrow = (wave >> 1) * 64, wcol = (wave & 1) * 64;
  int r0 = wave * 32;  // this wave's staging row base (32 rows per wave)
  int srow = lane >> 3;
  int schunk = (lane & 7) ^ srow;  // pre-swizzled global source chunk

  // read-side swizzled chunk offsets (u16 units): logical chunk (ks*4+quad) ^ (row&7)
  int koff0 = ((quad ^ (lr & 7)) << 3);
  int koff1 = (((4 | quad) ^ (lr & 7)) << 3);

  f32x4 zero = {0.f, 0.f, 0.f, 0.f};
  f32x4 acc[4][4];
#pragma unroll
  for (int i = 0; i < 4; i++)
#pragma unroll
    for (int j = 0; j < 4; j++) acc[i][j] = zero;

  const u16* ga = X + (size_t)(m0 + r0 + srow) * K + schunk * 8;
  const u16* gb = WT + (size_t)(n0 + r0 + srow) * K + schunk * 8;

  // prologue: stage tile 0 (8 loads/thread: 4 A-rowgroups + 4 B-rowgroups)
#pragma unroll
  for (int l = 0; l < 4; l++) {
    load_lds16(ga + (size_t)(l * 8) * K, &As[0][(r0 + l * 8) * 64]);
    load_lds16(gb + (size_t)(l * 8) * K, &Bs[0][(r0 + l * 8) * 64]);
  }

  int buf = 0;
  for (int k0 = 0; k0 < K; k0 += 64) {
    __syncthreads();  // drains tile-k0 loads (issued one compute phase ago)
    if (k0 + 64 < K) {
#pragma unroll
      for (int l = 0; l < 4; l++) {
        load_lds16(ga + (size_t)(l * 8) * K + k0 + 64, &As[buf ^ 1][(r0 + l * 8) * 64]);
        load_lds16(gb + (size_t)(l * 8) * K + k0 + 64, &Bs[buf ^ 1][(r0 + l * 8) * 64]);
      }
    }
    bfrag8 af[4][2], bf[4][2];
#pragma unroll
    for (int i = 0; i < 4; i++) {
      const u16* ar = &As[buf][(wrow + i * 16 + lr) * 64];
      af[i][0] = *(const bfrag8*)(ar + koff0);
      af[i][1] = *(const bfrag8*)(ar + koff1);
    }
#pragma unroll
    for (int j = 0; j < 4; j++) {
      const u16* br = &Bs[buf][(wcol + j * 16 + lr) * 64];
      bf[j][0] = *(const bfrag8*)(br + koff0);
      bf[j][1] = *(const bfrag8*)(br + koff1);
    }
#pragma unroll
    for (int i = 0; i < 4; i++)
#pragma unroll
      for (int j = 0; j < 4; j++) {
        acc[i][j] = MFMA_BF16(af[i][0], bf[j][0], acc[i][j]);
        acc[i][j] = MFMA_BF16(af[i][1], bf[j][1], acc[i][j]);
      }
    buf ^= 1;
  }

  int colbase = n0 + wcol;
  int which = colbase >> 10;  // 0=q 1=k 2=v
  int h = (colbase & 1023) >> 6;
  if (which < 2) {
    u16* dst = which == 0 ? qb : kb;
    // q pre-scaled by 1/8 * log2(e): attn computes P = exp2(S) directly
    float sc0 = (which == 0) ? 0.18033688011112042f : 1.0f;
    float fr0 = __expf(-0.28782313662425574f * (float)lr);        // ln(10000)/32
    float fr1 = __expf(-0.28782313662425574f * (float)(16 + lr));
#pragma unroll
    for (int i = 0; i < 4; i++) {
#pragma unroll
      for (int r = 0; r < 4; r++) {
        int m = m0 + wrow + i * 16 + quad * 4 + r;
        int b = m >> 11, tt = m & 2047;
        size_t base = ((size_t)(b * H_ + h) * T_ + tt) * D_;
        float sn, cs;
        __sincosf((float)tt * fr0, &sn, &cs);
        dst[base + lr] = f2bf((acc[i][0][r] * cs - acc[i][2][r] * sn) * sc0);
        dst[base + lr + 32] = f2bf((acc[i][0][r] * sn + acc[i][2][r] * cs) * sc0);
        __sincosf((float)tt * fr1, &sn, &cs);
        dst[base + 16 + lr] = f2bf((acc[i][1][r] * cs - acc[i][3][r] * sn) * sc0);
        dst[base + 48 + lr] = f2bf((acc[i][1][r] * sn + acc[i][3][r] * cs) * sc0);
      }
    }
  } else {
    // V: write transposed [bh][d][t]; lane holds 4 consecutive t per (i,j) -> 8B store
#pragma unroll
    for (int i = 0; i < 4; i++) {
      int mb = m0 + wrow + i * 16 + quad * 4;  // 4 consecutive t from here (same b)
      int b = mb >> 11, tt = mb & 2047;
      u16* vb = vtb + ((size_t)(b * H_ + h) * D_) * T_ + tt;
#pragma unroll
      for (int j = 0; j < 4; j++) {
        union { uint2 v; u16 hh[4]; } pk;
#pragma unroll
        for (int r = 0; r < 4; r++) pk.hh[r] = f2bf(acc[i][j][r]);
        *(uint2*)(vb + (size_t)(j * 16 + lr) * T_) = pk.v;
      }
    }
  }
}

// -------- attention: causal, S^T formulation, q-tile 128 (8 waves, 512 thr,
// 16 q-rows/wave). kv staging tile 128 (2 compute subtiles of 64 per barrier);
// Pst chunk16-XOR swizzled; 80KB LDS = 2 blocks/CU. (r12 exact, FROZEN) ----
__global__ __launch_bounds__(512) void attn_k(const u16* __restrict__ qb,
                                              const u16* __restrict__ kb,
                                              const u16* __restrict__ vtb,
                                              u16* __restrict__ ob) {
  __shared__ __align__(16) u16 Ks[2][128 * 64];  // [t][chunk^(t&7)]   16 KB each
  __shared__ __align__(16) u16 Vt[2][64 * 128];  // [d][chunk16^(d&7)] 16 KB each
  __shared__ __align__(16) u16 Pst[8][16 * 64];  // per-wave P, chunk16-XOR swizzled
  int tid = threadIdx.x;
  int lane = tid & 63, wave = tid >> 6;
  int quad = lane >> 4, lr = lane & 15;
  int i = blockIdx.x;
  int bq = 15 - (i >> 5);  // heavy blocks dispatched first (16 q-blocks of 128)
  int bh = i & 31;
  int b = bh >> 4, h2 = bh & 15;
  const u16* Q = qb + (size_t)bh * T_ * D_;
  const u16* Kp = kb + (size_t)bh * T_ * D_;
  const u16* Vp = vtb + (size_t)bh * D_ * T_;
  int qr0 = bq * 128 + wave * 16;  // this wave's q-row base

  // K staging: 16 rows/wave, 2 calls of 8 rows; 8 lanes/row, chunk pre-swizzled
  int rK = lane >> 3;
  int cK = ((lane & 7) ^ rK) * 8;
  const u16* gk0 = Kp + (size_t)(wave * 16 + rK) * D_ + cK;
  const u16* gk1 = gk0 + (size_t)8 * D_;
  // V staging: 8 d-rows/wave (256B each), 2 calls of 4 rows; 16 lanes/row
  int rV = lane >> 4;
  int cV = (lane & 15) ^ rV;  // call0 source chunk16; call1 = cV^4 (row&7 += 4)
  const u16* gv0 = Vp + (size_t)(wave * 8 + rV) * T_ + cV * 8;
  const u16* gv1 = Vp + (size_t)(wave * 8 + 4 + rV) * T_ + (cV ^ 4) * 8;

  // read-side swizzled chunk offsets (u16 units), constant per lane
  int koff0 = ((quad ^ (lr & 7)) << 3);
  int koff1 = (((4 | quad) ^ (lr & 7)) << 3);
  int lsw = lr & 7;

  // Q fragment as MFMA B-operand: B[n=q][k=d] (from global, unswizzled)
  bfrag8 qf[2];
#pragma unroll
  for (int ks = 0; ks < 2; ks++)
    qf[ks] = *(const bfrag8*)(Q + (size_t)(qr0 + lr) * D_ + ks * 32 + quad * 8);

  f32x4 zero = {0.f, 0.f, 0.f, 0.f};
  f32x4 o[4];
#pragma unroll
  for (int nn = 0; nn < 4; nn++) o[nn] = zero;
  float ps0 = 0.f, ps1 = 0.f, ps2 = 0.f, ps3 = 0.f;

  int nkt = bq + 1;                  // kv 128-tiles
  int wlast = 2 * bq + (wave >> 2);  // this wave's causal last SUBTILE (64-granule)
  int qloc = (wave & 3) * 16 + lr;   // q-pos within last subtile

  // prologue: stage kv-tile 0 (4 calls/thread)
  load_lds16(gk0, &Ks[0][(wave * 16) * 64]);
  load_lds16(gk1, &Ks[0][(wave * 16 + 8) * 64]);
  load_lds16(gv0, &Vt[0][(wave * 8) * 128]);
  load_lds16(gv1, &Vt[0][(wave * 8 + 4) * 128]);

  int buf = 0;
  for (int kt = 0; kt < nkt; kt++) {
    __syncthreads();  // drains tile-kt loads (issued one compute phase ago)
    if (kt + 1 < nkt) {
      int tb = (kt + 1) * 128;
      load_lds16(gk0 + (size_t)tb * D_, &Ks[buf ^ 1][(wave * 16) * 64]);
      load_lds16(gk1 + (size_t)tb * D_, &Ks[buf ^ 1][(wave * 16 + 8) * 64]);
      load_lds16(gv0 + tb, &Vt[buf ^ 1][(wave * 8) * 128]);
      load_lds16(gv1 + tb, &Vt[buf ^ 1][(wave * 8 + 4) * 128]);
    }
    const u16* ks_ = Ks[buf];
    const u16* vt_ = Vt[buf];
#pragma unroll
    for (int h = 0; h < 2; h++) {
      int st = 2 * kt + h;
      if (st <= wlast) {  // wave-uniform
        // S^T = K Q^T : 64 kv-rows x 16 q-cols (A=K-frag swizzled, B=Q-frag)
        f32x4 s[4];
#pragma unroll
        for (int j = 0; j < 4; j++) s[j] = zero;
#pragma unroll
        for (int j = 0; j < 4; j++) {
          const u16* kr = &ks_[(h * 64 + j * 16 + lr) * 64];
          bfrag8 kf0 = *(const bfrag8*)(kr + koff0);
          bfrag8 kf1 = *(const bfrag8*)(kr + koff1);
          s[j] = MFMA_BF16(kf0, qf[0], s[j]);
          s[j] = MFMA_BF16(kf1, qf[1], s[j]);
        }

        // P = exp2(S) + manual pair-pack + 4-way psum; Pst chunk16-XOR swizzled
        bool edge = (st == wlast);  // wave-uniform
#pragma unroll
        for (int j = 0; j < 4; j++) {
          float p[4];
#pragma unroll
          for (int r = 0; r < 4; r++) {
            float e = exp2_fast(s[j][r]);
            if (edge) {
              int kvloc = j * 16 + quad * 4 + r;
              e = (kvloc <= qloc) ? e : 0.f;
            }
            p[r] = e;
          }
          ps0 += p[0];
          ps1 += p[1];
          ps2 += p[2];
          ps3 += p[3];
          u32 u0 = __builtin_bit_cast(u32, p[0]) + 0x8000u;
          u32 u1 = __builtin_bit_cast(u32, p[1]) + 0x8000u;
          u32 u2 = __builtin_bit_cast(u32, p[2]) + 0x8000u;
          u32 u3 = __builtin_bit_cast(u32, p[3]) + 0x8000u;
          uint2 pk;
          pk.x = (u0 >> 16) | (u1 & 0xffff0000u);
          pk.y = (u2 >> 16) | (u3 & 0xffff0000u);
          // logical 16B-chunk (2j + quad>>1), half (quad&1), stored at chunk^lsw
          *(uint2*)&Pst[wave][lr * 64 + (((2 * j + (quad >> 1)) ^ lsw) << 3) +
                              ((quad & 1) << 2)] = pk;
        }

        // O += P V : A = P[q][t] (b128, swizzled), B = V^T[d][t] (swizzled, 128-wide)
#pragma unroll
        for (int ks = 0; ks < 2; ks++) {
          bfrag8 pf = *(const bfrag8*)&Pst[wave][lr * 64 + (((4 * ks + quad) ^ lsw) << 3)];
#pragma unroll
          for (int nn = 0; nn < 4; nn++) {
            int vko = ((8 * h + 4 * ks + quad) ^ lsw) << 3;
            bfrag8 vf = *(const bfrag8*)&vt_[(nn * 16 + lr) * 128 + vko];
            o[nn] = MFMA_BF16(pf, vf, o[nn]);
          }
        }
      }
    }
    buf ^= 1;
  }

  // total row-sum: reduce over the 4 quads
  float l = (ps0 + ps1) + (ps2 + ps3);
  l += __shfl_xor(l, 16, 64);
  l += __shfl_xor(l, 32, 64);
  float linv = 1.0f / l;

#pragma unroll
  for (int r = 0; r < 4; r++) {
    float lrec = __shfl(linv, quad * 4 + r, 64);
    int row = qr0 + quad * 4 + r;
#pragma unroll
    for (int nn = 0; nn < 4; nn++)
      ob[(size_t)(b * T_ + row) * C_ + h2 * 64 + nn * 16 + lr] = f2bf(o[nn][r] * lrec);
  }
}

// -------- GEMM 2: out(f32) = A(4096x1024)bf16 @ WT(1024x1024)bf16 + bias(f32).
// 64x128 tile (grid 512), BK=64 + chunk-XOR swizzle (r7 exact, FROZEN). --------
__global__ __launch_bounds__(256) void gemm_proj(const u16* __restrict__ A,
                                                 const u16* __restrict__ WT,
                                                 const float* __restrict__ bias,
                                                 float* __restrict__ out) {
  const int K = C_;
  __shared__ __align__(16) u16 As[2][64 * 64];   // 16 KB
  __shared__ __align__(16) u16 Bs[2][128 * 64];  // 32 KB
  int tid = threadIdx.x;
  int lane = tid & 63, wave = tid >> 6;
  int quad = lane >> 4, lr = lane & 15;
  int m0 = blockIdx.y * 64, n0 = blockIdx.x * 128;
  int wcol = wave * 32;
  int srow = lane >> 3;
  int schunk = (lane & 7) ^ srow;  // pre-swizzled global source chunk

  int koff0 = ((quad ^ (lr & 7)) << 3);
  int koff1 = (((4 | quad) ^ (lr & 7)) << 3);

  f32x4 zero = {0.f, 0.f, 0.f, 0.f};
  f32x4 acc[4][2];
#pragma unroll
  for (int i = 0; i < 4; i++)
#pragma unroll
    for (int j = 0; j < 2; j++) acc[i][j] = zero;

  const u16* ga = A + (size_t)(m0 + wave * 16 + srow) * K + schunk * 8;
  const u16* gb = WT + (size_t)(n0 + wave * 32 + srow) * K + schunk * 8;

  // prologue: A rows wave*16 + {0,8}; B rows wave*32 + {0,8,16,24}
  load_lds16(ga, &As[0][(wave * 16) * 64]);
  load_lds16(ga + (size_t)8 * K, &As[0][(wave * 16 + 8) * 64]);
#pragma unroll
  for (int l = 0; l < 4; l++)
    load_lds16(gb + (size_t)(l * 8) * K, &Bs[0][(wave * 32 + l * 8) * 64]);

  int buf = 0;
  for (int k0 = 0; k0 < K; k0 += 64) {
    __syncthreads();
    if (k0 + 64 < K) {
      load_lds16(ga + k0 + 64, &As[buf ^ 1][(wave * 16) * 64]);
      load_lds16(ga + (size_t)8 * K + k0 + 64, &As[buf ^ 1][(wave * 16 + 8) * 64]);
#pragma unroll
      for (int l = 0; l < 4; l++)
        load_lds16(gb + (size_t)(l * 8) * K + k0 + 64, &Bs[buf ^ 1][(wave * 32 + l * 8) * 64]);
    }
    bfrag8 af[4][2], bf[2][2];
#pragma unroll
    for (int i = 0; i < 4; i++) {
      const u16* ar = &As[buf][(i * 16 + lr) * 64];
      af[i][0] = *(const bfrag8*)(ar + koff0);
      af[i][1] = *(const bfrag8*)(ar + koff1);
    }
#pragma unroll
    for (int j = 0; j < 2; j++) {
      const u16* br = &Bs[buf][(wcol + j * 16 + lr) * 64];
      bf[j][0] = *(const bfrag8*)(br + koff0);
      bf[j][1] = *(const bfrag8*)(br + koff1);
    }
#pragma unroll
    for (int i = 0; i < 4; i++)
#pragma unroll
      for (int j = 0; j < 2; j++) {
        acc[i][j] = MFMA_BF16(af[i][0], bf[j][0], acc[i][j]);
        acc[i][j] = MFMA_BF16(af[i][1], bf[j][1], acc[i][j]);
      }
    buf ^= 1;
  }

#pragma unroll
  for (int i = 0; i < 4; i++)
#pragma unroll
    for (int r = 0; r < 4; r++) {
      int m = m0 + i * 16 + quad * 4 + r;
#pragma unroll
      for (int j = 0; j < 2; j++) {
        int n = n0 + wcol + j * 16 + lr;
        out[(size_t)m * C_ + n] = acc[i][j][r] + bias[n];
      }
    }
}

extern "C" void kernel_launch(void* const* d_in, const int* in_sizes, int n_in,
                              void* d_out, int out_size, void* d_ws, size_t ws_size,
                              hipStream_t stream) {
  const float* x = (const float*)d_in[0];       // [4096,1024] f32
  const float* w_qkv = (const float*)d_in[1];   // [1024,3072] f32
  const float* w_proj = (const float*)d_in[2];  // [1024,1024] f32
  const float* b_proj = (const float*)d_in[3];  // [1024] f32

  char* w = (char*)d_ws;
  u16* xb = (u16*)(w + 256);                 // 4096*1024 bf16 (A for gemm_qkv)
  u16* regA = xb + (size_t)4096 * 1024;      // max(wqkvT, abuf)
  u16* wqkvT = regA;                         // 3072*1024 (dead after gemm_qkv)
  u16* abuf = regA;                          // 4096*1024 (written by attn)
  u16* wprojT = regA + (size_t)4096 * 1024;  // 1024*1024
  u16* qbuf = wprojT + (size_t)1024 * 1024;
  u16* kbuf = qbuf + (size_t)B_ * H_ * T_ * D_;
  u16* vtb = kbuf + (size_t)B_ * H_ * T_ * D_;  // V^T [bh][d][t] (written by gemm_qkv)

  prep<<<3072, 256, 0, stream>>>(x, xb, w_qkv, wqkvT, w_proj, wprojT);
  gemm_qkv_rope<<<dim3(NQKV_ / 128, (B_ * T_) / 128), 256, 0, stream>>>(xb, wqkvT, qbuf, kbuf, vtb);
  attn_k<<<512, 512, 0, stream>>>(qbuf, kbuf, vtb, abuf);
  gemm_proj<<<dim3(C_ / 128, (B_ * T_) / 64), 256, 0, stream>>>(abuf, wprojT, b_proj, (float*)d_out);
}

// Round 15
// 179.305 us; speedup vs baseline: 1.0018x; 1.0018x over previous
//
#include <hip/hip_runtime.h>
#include <math.h>

typedef unsigned short u16;
typedef unsigned int u32;
typedef __bf16 bfrag8 __attribute__((ext_vector_type(8)));
typedef float f32x4 __attribute__((ext_vector_type(4)));

#define B_ 2
#define T_ 2048
#define H_ 16
#define D_ 64
#define C_ 1024
#define NQKV_ 3072

#define MFMA_BF16(a, b, c) __builtin_amdgcn_mfma_f32_16x16x32_bf16((a), (b), (c), 0, 0, 0)

__device__ __forceinline__ u16 f2bf(float f) {
  u32 u = __builtin_bit_cast(u32, f);
  u += 0x7fffu + ((u >> 16) & 1u);  // RNE
  return (u16)(u >> 16);
}

// exp2 via the target builtin: single v_exp_f32 with compiler-managed TRANS hazard
__device__ __forceinline__ float exp2_fast(float x) {
#if __has_builtin(__builtin_amdgcn_exp2f)
  return __builtin_amdgcn_exp2f(x);
#else
  return __expf(x * 0.6931471805599453f);
#endif
}

// async global->LDS, 16B/lane; lds dest = wave-uniform base + lane*16
__device__ __forceinline__ void load_lds16(const u16* gp, u16* lp) {
  __builtin_amdgcn_global_load_lds(
      (const __attribute__((address_space(1))) u32*)(const void*)gp,
      (__attribute__((address_space(3))) u32*)(void*)lp, 16, 0, 0);
}

// -------- fused prep: convert x (f32->bf16) + transpose both weights. --------
__global__ __launch_bounds__(256) void prep(const float* __restrict__ x,
                                            u16* __restrict__ xb,
                                            const float* __restrict__ wqkv,
                                            u16* __restrict__ wqkvT,
                                            const float* __restrict__ wproj,
                                            u16* __restrict__ wprojT) {
  int bid = blockIdx.x;
  int tid = threadIdx.x;
  __shared__ u16 tile[64][65];
  if (bid < 2048) {
    size_t i = ((size_t)bid * 256 + tid) * 8;
    const float* s = x + i;
    float4 a = *(const float4*)s, b = *(const float4*)(s + 4);
    union { uint4 v; u16 h[8]; } t;
    t.h[0] = f2bf(a.x); t.h[1] = f2bf(a.y); t.h[2] = f2bf(a.z); t.h[3] = f2bf(a.w);
    t.h[4] = f2bf(b.x); t.h[5] = f2bf(b.y); t.h[6] = f2bf(b.z); t.h[7] = f2bf(b.w);
    *(uint4*)(xb + i) = t.v;
    return;
  }
  const float* src;
  u16* dst;
  int N, bx, by;
  if (bid < 2816) {
    int rel = bid - 2048;
    src = wqkv; dst = wqkvT; N = NQKV_;
    bx = (rel % 48) * 64; by = (rel / 48) * 64;
  } else {
    int rel = bid - 2816;
    src = wproj; dst = wprojT; N = C_;
    bx = (rel & 15) * 64; by = (rel >> 4) * 64;
  }
  for (int idx = tid; idx < 4096; idx += 256) {
    int r = idx >> 6, c = idx & 63;
    tile[r][c] = f2bf(src[(size_t)(by + r) * N + bx + c]);
  }
  __syncthreads();
  for (int idx = tid; idx < 4096; idx += 256) {
    int r = idx >> 6, c = idx & 63;
    dst[(size_t)(bx + r) * C_ + by + c] = tile[c][r];
  }
}

// -------- GEMM 1: qkv = X(4096x1024)bf16 @ WT(3072x1024)bf16, RoPE epilogue.
// 128x128 tile, BK=64, dbuf chunk-XOR-swizzled LDS (r5-proven, conflicts=0). FROZEN
// — 4 structural rewrites (8-phase, depth-2 vmcnt, B-direct, 192-tile) all lost.
// q pre-scaled by 0.125*log2e: attn computes P = exp2(S) directly. --------
__global__ __launch_bounds__(256) void gemm_qkv_rope(const u16* __restrict__ X,
                                                     const u16* __restrict__ WT,
                                                     u16* __restrict__ qb,
                                                     u16* __restrict__ kb,
                                                     u16* __restrict__ vtb) {
  const int K = C_;
  __shared__ __align__(16) u16 As[2][128 * 64];  // 32 KB
  __shared__ __align__(16) u16 Bs[2][128 * 64];  // 32 KB
  int tid = threadIdx.x;
  int lane = tid & 63, wave = tid >> 6;
  int quad = lane >> 4, lr = lane & 15;
  int m0 = blockIdx.y * 128, n0 = blockIdx.x * 128;
  int wrow = (wave >> 1) * 64, wcol = (wave & 1) * 64;
  int r0 = wave * 32;  // this wave's staging row base (32 rows per wave)
  int srow = lane >> 3;
  int schunk = (lane & 7) ^ srow;  // pre-swizzled global source chunk

  // read-side swizzled chunk offsets (u16 units): logical chunk (ks*4+quad) ^ (row&7)
  int koff0 = ((quad ^ (lr & 7)) << 3);
  int koff1 = (((4 | quad) ^ (lr & 7)) << 3);

  f32x4 zero = {0.f, 0.f, 0.f, 0.f};
  f32x4 acc[4][4];
#pragma unroll
  for (int i = 0; i < 4; i++)
#pragma unroll
    for (int j = 0; j < 4; j++) acc[i][j] = zero;

  const u16* ga = X + (size_t)(m0 + r0 + srow) * K + schunk * 8;
  const u16* gb = WT + (size_t)(n0 + r0 + srow) * K + schunk * 8;

  // prologue: stage tile 0 (8 loads/thread: 4 A-rowgroups + 4 B-rowgroups)
#pragma unroll
  for (int l = 0; l < 4; l++) {
    load_lds16(ga + (size_t)(l * 8) * K, &As[0][(r0 + l * 8) * 64]);
    load_lds16(gb + (size_t)(l * 8) * K, &Bs[0][(r0 + l * 8) * 64]);
  }

  int buf = 0;
  for (int k0 = 0; k0 < K; k0 += 64) {
    __syncthreads();  // drains tile-k0 loads (issued one compute phase ago)
    if (k0 + 64 < K) {
#pragma unroll
      for (int l = 0; l < 4; l++) {
        load_lds16(ga + (size_t)(l * 8) * K + k0 + 64, &As[buf ^ 1][(r0 + l * 8) * 64]);
        load_lds16(gb + (size_t)(l * 8) * K + k0 + 64, &Bs[buf ^ 1][(r0 + l * 8) * 64]);
      }
    }
    bfrag8 af[4][2], bf[4][2];
#pragma unroll
    for (int i = 0; i < 4; i++) {
      const u16* ar = &As[buf][(wrow + i * 16 + lr) * 64];
      af[i][0] = *(const bfrag8*)(ar + koff0);
      af[i][1] = *(const bfrag8*)(ar + koff1);
    }
#pragma unroll
    for (int j = 0; j < 4; j++) {
      const u16* br = &Bs[buf][(wcol + j * 16 + lr) * 64];
      bf[j][0] = *(const bfrag8*)(br + koff0);
      bf[j][1] = *(const bfrag8*)(br + koff1);
    }
#pragma unroll
    for (int i = 0; i < 4; i++)
#pragma unroll
      for (int j = 0; j < 4; j++) {
        acc[i][j] = MFMA_BF16(af[i][0], bf[j][0], acc[i][j]);
        acc[i][j] = MFMA_BF16(af[i][1], bf[j][1], acc[i][j]);
      }
    buf ^= 1;
  }

  int colbase = n0 + wcol;
  int which = colbase >> 10;  // 0=q 1=k 2=v
  int h = (colbase & 1023) >> 6;
  if (which < 2) {
    u16* dst = which == 0 ? qb : kb;
    // q pre-scaled by 1/8 * log2(e): attn computes P = exp2(S) directly
    float sc0 = (which == 0) ? 0.18033688011112042f : 1.0f;
    float fr0 = __expf(-0.28782313662425574f * (float)lr);        // ln(10000)/32
    float fr1 = __expf(-0.28782313662425574f * (float)(16 + lr));
#pragma unroll
    for (int i = 0; i < 4; i++) {
#pragma unroll
      for (int r = 0; r < 4; r++) {
        int m = m0 + wrow + i * 16 + quad * 4 + r;
        int b = m >> 11, tt = m & 2047;
        size_t base = ((size_t)(b * H_ + h) * T_ + tt) * D_;
        float sn, cs;
        __sincosf((float)tt * fr0, &sn, &cs);
        dst[base + lr] = f2bf((acc[i][0][r] * cs - acc[i][2][r] * sn) * sc0);
        dst[base + lr + 32] = f2bf((acc[i][0][r] * sn + acc[i][2][r] * cs) * sc0);
        __sincosf((float)tt * fr1, &sn, &cs);
        dst[base + 16 + lr] = f2bf((acc[i][1][r] * cs - acc[i][3][r] * sn) * sc0);
        dst[base + 48 + lr] = f2bf((acc[i][1][r] * sn + acc[i][3][r] * cs) * sc0);
      }
    }
  } else {
    // V: write transposed [bh][d][t]; lane holds 4 consecutive t per (i,j) -> 8B store
#pragma unroll
    for (int i = 0; i < 4; i++) {
      int mb = m0 + wrow + i * 16 + quad * 4;  // 4 consecutive t from here (same b)
      int b = mb >> 11, tt = mb & 2047;
      u16* vb = vtb + ((size_t)(b * H_ + h) * D_) * T_ + tt;
#pragma unroll
      for (int j = 0; j < 4; j++) {
        union { uint2 v; u16 hh[4]; } pk;
#pragma unroll
        for (int r = 0; r < 4; r++) pk.hh[r] = f2bf(acc[i][j][r]);
        *(uint2*)(vb + (size_t)(j * 16 + lr) * T_) = pk.v;
      }
    }
  }
}

// -------- attention: causal, S^T formulation, q-tile 128 (8 waves, 512 thr,
// 16 q-rows/wave). kv staging tile 128 (2 subtiles/barrier); Pst chunk16-XOR
// swizzled; 80KB LDS = 2 blocks/CU, grid 512 = all co-resident in ONE round.
// r15: BALANCED dispatch pairing — makespan = slowest CU. Old heavy-first order
// put bq 15..8 in blocks 0..255 and 7..0 in 256..511, so round-robin placement
// paired heavy-with-heavy (CU work 24..10 units, avg 17). New order pairs block k
// (bq=15-(k>>5)) with k+256 (bq=(k>>5)) -> every CU sums to 17 units, constant.
// Placement is a perf heuristic only (correctness placement-independent). ----
__global__ __launch_bounds__(512) void attn_k(const u16* __restrict__ qb,
                                              const u16* __restrict__ kb,
                                              const u16* __restrict__ vtb,
                                              u16* __restrict__ ob) {
  __shared__ __align__(16) u16 Ks[2][128 * 64];  // [t][chunk^(t&7)]   16 KB each
  __shared__ __align__(16) u16 Vt[2][64 * 128];  // [d][chunk16^(d&7)] 16 KB each
  __shared__ __align__(16) u16 Pst[8][16 * 64];  // per-wave P, chunk16-XOR swizzled
  int tid = threadIdx.x;
  int lane = tid & 63, wave = tid >> 6;
  int quad = lane >> 4, lr = lane & 15;
  int i = blockIdx.x;
  // balanced pairing: i<256 -> bq 15..8 (heavy, dispatched first);
  // i>=256 -> bq 0..7 so that blocks i and i+256 sum to constant work.
  int bq = (i < 256) ? (15 - (i >> 5)) : ((i >> 5) - 8);
  int bh = i & 31;
  int b = bh >> 4, h2 = bh & 15;
  const u16* Q = qb + (size_t)bh * T_ * D_;
  const u16* Kp = kb + (size_t)bh * T_ * D_;
  const u16* Vp = vtb + (size_t)bh * D_ * T_;
  int qr0 = bq * 128 + wave * 16;  // this wave's q-row base

  // K staging: 16 rows/wave, 2 calls of 8 rows; 8 lanes/row, chunk pre-swizzled
  int rK = lane >> 3;
  int cK = ((lane & 7) ^ rK) * 8;
  const u16* gk0 = Kp + (size_t)(wave * 16 + rK) * D_ + cK;
  const u16* gk1 = gk0 + (size_t)8 * D_;
  // V staging: 8 d-rows/wave (256B each), 2 calls of 4 rows; 16 lanes/row
  int rV = lane >> 4;
  int cV = (lane & 15) ^ rV;  // call0 source chunk16; call1 = cV^4 (row&7 += 4)
  const u16* gv0 = Vp + (size_t)(wave * 8 + rV) * T_ + cV * 8;
  const u16* gv1 = Vp + (size_t)(wave * 8 + 4 + rV) * T_ + (cV ^ 4) * 8;

  // read-side swizzled chunk offsets (u16 units), constant per lane
  int koff0 = ((quad ^ (lr & 7)) << 3);
  int koff1 = (((4 | quad) ^ (lr & 7)) << 3);
  int lsw = lr & 7;

  // Q fragment as MFMA B-operand: B[n=q][k=d] (from global, unswizzled)
  bfrag8 qf[2];
#pragma unroll
  for (int ks = 0; ks < 2; ks++)
    qf[ks] = *(const bfrag8*)(Q + (size_t)(qr0 + lr) * D_ + ks * 32 + quad * 8);

  f32x4 zero = {0.f, 0.f, 0.f, 0.f};
  f32x4 o[4];
#pragma unroll
  for (int nn = 0; nn < 4; nn++) o[nn] = zero;
  float ps0 = 0.f, ps1 = 0.f, ps2 = 0.f, ps3 = 0.f;

  int nkt = bq + 1;                  // kv 128-tiles
  int wlast = 2 * bq + (wave >> 2);  // this wave's causal last SUBTILE (64-granule)
  int qloc = (wave & 3) * 16 + lr;   // q-pos within last subtile

  // prologue: stage kv-tile 0 (4 calls/thread)
  load_lds16(gk0, &Ks[0][(wave * 16) * 64]);
  load_lds16(gk1, &Ks[0][(wave * 16 + 8) * 64]);
  load_lds16(gv0, &Vt[0][(wave * 8) * 128]);
  load_lds16(gv1, &Vt[0][(wave * 8 + 4) * 128]);

  int buf = 0;
  for (int kt = 0; kt < nkt; kt++) {
    __syncthreads();  // drains tile-kt loads (issued one compute phase ago)
    if (kt + 1 < nkt) {
      int tb = (kt + 1) * 128;
      load_lds16(gk0 + (size_t)tb * D_, &Ks[buf ^ 1][(wave * 16) * 64]);
      load_lds16(gk1 + (size_t)tb * D_, &Ks[buf ^ 1][(wave * 16 + 8) * 64]);
      load_lds16(gv0 + tb, &Vt[buf ^ 1][(wave * 8) * 128]);
      load_lds16(gv1 + tb, &Vt[buf ^ 1][(wave * 8 + 4) * 128]);
    }
    const u16* ks_ = Ks[buf];
    const u16* vt_ = Vt[buf];
#pragma unroll
    for (int h = 0; h < 2; h++) {
      int st = 2 * kt + h;
      if (st <= wlast) {  // wave-uniform
        // S^T = K Q^T : 64 kv-rows x 16 q-cols (A=K-frag swizzled, B=Q-frag)
        f32x4 s[4];
#pragma unroll
        for (int j = 0; j < 4; j++) s[j] = zero;
#pragma unroll
        for (int j = 0; j < 4; j++) {
          const u16* kr = &ks_[(h * 64 + j * 16 + lr) * 64];
          bfrag8 kf0 = *(const bfrag8*)(kr + koff0);
          bfrag8 kf1 = *(const bfrag8*)(kr + koff1);
          s[j] = MFMA_BF16(kf0, qf[0], s[j]);
          s[j] = MFMA_BF16(kf1, qf[1], s[j]);
        }

        // P = exp2(S) + manual pair-pack + 4-way psum; Pst chunk16-XOR swizzled
        bool edge = (st == wlast);  // wave-uniform
#pragma unroll
        for (int j = 0; j < 4; j++) {
          float p[4];
#pragma unroll
          for (int r = 0; r < 4; r++) {
            float e = exp2_fast(s[j][r]);
            if (edge) {
              int kvloc = j * 16 + quad * 4 + r;
              e = (kvloc <= qloc) ? e : 0.f;
            }
            p[r] = e;
          }
          ps0 += p[0];
          ps1 += p[1];
          ps2 += p[2];
          ps3 += p[3];
          u32 u0 = __builtin_bit_cast(u32, p[0]) + 0x8000u;
          u32 u1 = __builtin_bit_cast(u32, p[1]) + 0x8000u;
          u32 u2 = __builtin_bit_cast(u32, p[2]) + 0x8000u;
          u32 u3 = __builtin_bit_cast(u32, p[3]) + 0x8000u;
          uint2 pk;
          pk.x = (u0 >> 16) | (u1 & 0xffff0000u);
          pk.y = (u2 >> 16) | (u3 & 0xffff0000u);
          // logical 16B-chunk (2j + quad>>1), half (quad&1), stored at chunk^lsw
          *(uint2*)&Pst[wave][lr * 64 + (((2 * j + (quad >> 1)) ^ lsw) << 3) +
                              ((quad & 1) << 2)] = pk;
        }

        // O += P V : A = P[q][t] (b128, swizzled), B = V^T[d][t] (swizzled, 128-wide)
#pragma unroll
        for (int ks = 0; ks < 2; ks++) {
          bfrag8 pf = *(const bfrag8*)&Pst[wave][lr * 64 + (((4 * ks + quad) ^ lsw) << 3)];
#pragma unroll
          for (int nn = 0; nn < 4; nn++) {
            int vko = ((8 * h + 4 * ks + quad) ^ lsw) << 3;
            bfrag8 vf = *(const bfrag8*)&vt_[(nn * 16 + lr) * 128 + vko];
            o[nn] = MFMA_BF16(pf, vf, o[nn]);
          }
        }
      }
    }
    buf ^= 1;
  }

  // total row-sum: reduce over the 4 quads
  float l = (ps0 + ps1) + (ps2 + ps3);
  l += __shfl_xor(l, 16, 64);
  l += __shfl_xor(l, 32, 64);
  float linv = 1.0f / l;

#pragma unroll
  for (int r = 0; r < 4; r++) {
    float lrec = __shfl(linv, quad * 4 + r, 64);
    int row = qr0 + quad * 4 + r;
#pragma unroll
    for (int nn = 0; nn < 4; nn++)
      ob[(size_t)(b * T_ + row) * C_ + h2 * 64 + nn * 16 + lr] = f2bf(o[nn][r] * lrec);
  }
}

// -------- GEMM 2: out(f32) = A(4096x1024)bf16 @ WT(1024x1024)bf16 + bias(f32).
// 64x128 tile (grid 512), BK=64 + chunk-XOR swizzle (r7 exact, FROZEN). --------
__global__ __launch_bounds__(256) void gemm_proj(const u16* __restrict__ A,
                                                 const u16* __restrict__ WT,
                                                 const float* __restrict__ bias,
                                                 float* __restrict__ out) {
  const int K = C_;
  __shared__ __align__(16) u16 As[2][64 * 64];   // 16 KB
  __shared__ __align__(16) u16 Bs[2][128 * 64];  // 32 KB
  int tid = threadIdx.x;
  int lane = tid & 63, wave = tid >> 6;
  int quad = lane >> 4, lr = lane & 15;
  int m0 = blockIdx.y * 64, n0 = blockIdx.x * 128;
  int wcol = wave * 32;
  int srow = lane >> 3;
  int schunk = (lane & 7) ^ srow;  // pre-swizzled global source chunk

  int koff0 = ((quad ^ (lr & 7)) << 3);
  int koff1 = (((4 | quad) ^ (lr & 7)) << 3);

  f32x4 zero = {0.f, 0.f, 0.f, 0.f};
  f32x4 acc[4][2];
#pragma unroll
  for (int i = 0; i < 4; i++)
#pragma unroll
    for (int j = 0; j < 2; j++) acc[i][j] = zero;

  const u16* ga = A + (size_t)(m0 + wave * 16 + srow) * K + schunk * 8;
  const u16* gb = WT + (size_t)(n0 + wave * 32 + srow) * K + schunk * 8;

  // prologue: A rows wave*16 + {0,8}; B rows wave*32 + {0,8,16,24}
  load_lds16(ga, &As[0][(wave * 16) * 64]);
  load_lds16(ga + (size_t)8 * K, &As[0][(wave * 16 + 8) * 64]);
#pragma unroll
  for (int l = 0; l < 4; l++)
    load_lds16(gb + (size_t)(l * 8) * K, &Bs[0][(wave * 32 + l * 8) * 64]);

  int buf = 0;
  for (int k0 = 0; k0 < K; k0 += 64) {
    __syncthreads();
    if (k0 + 64 < K) {
      load_lds16(ga + k0 + 64, &As[buf ^ 1][(wave * 16) * 64]);
      load_lds16(ga + (size_t)8 * K + k0 + 64, &As[buf ^ 1][(wave * 16 + 8) * 64]);
#pragma unroll
      for (int l = 0; l < 4; l++)
        load_lds16(gb + (size_t)(l * 8) * K + k0 + 64, &Bs[buf ^ 1][(wave * 32 + l * 8) * 64]);
    }
    bfrag8 af[4][2], bf[2][2];
#pragma unroll
    for (int i = 0; i < 4; i++) {
      const u16* ar = &As[buf][(i * 16 + lr) * 64];
      af[i][0] = *(const bfrag8*)(ar + koff0);
      af[i][1] = *(const bfrag8*)(ar + koff1);
    }
#pragma unroll
    for (int j = 0; j < 2; j++) {
      const u16* br = &Bs[buf][(wcol + j * 16 + lr) * 64];
      bf[j][0] = *(const bfrag8*)(br + koff0);
      bf[j][1] = *(const bfrag8*)(br + koff1);
    }
#pragma unroll
    for (int i = 0; i < 4; i++)
#pragma unroll
      for (int j = 0; j < 2; j++) {
        acc[i][j] = MFMA_BF16(af[i][0], bf[j][0], acc[i][j]);
        acc[i][j] = MFMA_BF16(af[i][1], bf[j][1], acc[i][j]);
      }
    buf ^= 1;
  }

#pragma unroll
  for (int i = 0; i < 4; i++)
#pragma unroll
    for (int r = 0; r < 4; r++) {
      int m = m0 + i * 16 + quad * 4 + r;
#pragma unroll
      for (int j = 0; j < 2; j++) {
        int n = n0 + wcol + j * 16 + lr;
        out[(size_t)m * C_ + n] = acc[i][j][r] + bias[n];
      }
    }
}

extern "C" void kernel_launch(void* const* d_in, const int* in_sizes, int n_in,
                              void* d_out, int out_size, void* d_ws, size_t ws_size,
                              hipStream_t stream) {
  const float* x = (const float*)d_in[0];       // [4096,1024] f32
  const float* w_qkv = (const float*)d_in[1];   // [1024,3072] f32
  const float* w_proj = (const float*)d_in[2];  // [1024,1024] f32
  const float* b_proj = (const float*)d_in[3];  // [1024] f32

  char* w = (char*)d_ws;
  u16* xb = (u16*)(w + 256);                 // 4096*1024 bf16 (A for gemm_qkv)
  u16* regA = xb + (size_t)4096 * 1024;      // max(wqkvT, abuf)
  u16* wqkvT = regA;                         // 3072*1024 (dead after gemm_qkv)
  u16* abuf = regA;                          // 4096*1024 (written by attn)
  u16* wprojT = regA + (size_t)4096 * 1024;  // 1024*1024
  u16* qbuf = wprojT + (size_t)1024 * 1024;
  u16* kbuf = qbuf + (size_t)B_ * H_ * T_ * D_;
  u16* vtb = kbuf + (size_t)B_ * H_ * T_ * D_;  // V^T [bh][d][t] (written by gemm_qkv)

  prep<<<3072, 256, 0, stream>>>(x, xb, w_qkv, wqkvT, w_proj, wprojT);
  gemm_qkv_rope<<<dim3(NQKV_ / 128, (B_ * T_) / 128), 256, 0, stream>>>(xb, wqkvT, qbuf, kbuf, vtb);
  attn_k<<<512, 512, 0, stream>>>(qbuf, kbuf, vtb, abuf);
  gemm_proj<<<dim3(C_ / 128, (B_ * T_) / 64), 256, 0, stream>>>(abuf, wprojT, b_proj, (float*)d_out);
}

// Round 16
// 178.813 us; speedup vs baseline: 1.0045x; 1.0028x over previous
//
#include <hip/hip_runtime.h>
#include <math.h>

typedef unsigned short u16;
typedef unsigned int u32;
typedef __bf16 bfrag8 __attribute__((ext_vector_type(8)));
typedef float f32x4 __attribute__((ext_vector_type(4)));

#define B_ 2
#define T_ 2048
#define H_ 16
#define D_ 64
#define C_ 1024
#define NQKV_ 3072

#define MFMA_BF16(a, b, c) __builtin_amdgcn_mfma_f32_16x16x32_bf16((a), (b), (c), 0, 0, 0)

__device__ __forceinline__ u16 f2bf(float f) {
  u32 u = __builtin_bit_cast(u32, f);
  u += 0x7fffu + ((u >> 16) & 1u);  // RNE
  return (u16)(u >> 16);
}

// exp2 via the target builtin: single v_exp_f32 with compiler-managed TRANS hazard
__device__ __forceinline__ float exp2_fast(float x) {
#if __has_builtin(__builtin_amdgcn_exp2f)
  return __builtin_amdgcn_exp2f(x);
#else
  return __expf(x * 0.6931471805599453f);
#endif
}

// async global->LDS, 16B/lane; lds dest = wave-uniform base + lane*16
__device__ __forceinline__ void load_lds16(const u16* gp, u16* lp) {
  __builtin_amdgcn_global_load_lds(
      (const __attribute__((address_space(1))) u32*)(const void*)gp,
      (__attribute__((address_space(3))) u32*)(void*)lp, 16, 0, 0);
}

// -------- fused prep: convert x (f32->bf16) + transpose both weights. --------
__global__ __launch_bounds__(256) void prep(const float* __restrict__ x,
                                            u16* __restrict__ xb,
                                            const float* __restrict__ wqkv,
                                            u16* __restrict__ wqkvT,
                                            const float* __restrict__ wproj,
                                            u16* __restrict__ wprojT) {
  int bid = blockIdx.x;
  int tid = threadIdx.x;
  __shared__ u16 tile[64][65];
  if (bid < 2048) {
    size_t i = ((size_t)bid * 256 + tid) * 8;
    const float* s = x + i;
    float4 a = *(const float4*)s, b = *(const float4*)(s + 4);
    union { uint4 v; u16 h[8]; } t;
    t.h[0] = f2bf(a.x); t.h[1] = f2bf(a.y); t.h[2] = f2bf(a.z); t.h[3] = f2bf(a.w);
    t.h[4] = f2bf(b.x); t.h[5] = f2bf(b.y); t.h[6] = f2bf(b.z); t.h[7] = f2bf(b.w);
    *(uint4*)(xb + i) = t.v;
    return;
  }
  const float* src;
  u16* dst;
  int N, bx, by;
  if (bid < 2816) {
    int rel = bid - 2048;
    src = wqkv; dst = wqkvT; N = NQKV_;
    bx = (rel % 48) * 64; by = (rel / 48) * 64;
  } else {
    int rel = bid - 2816;
    src = wproj; dst = wprojT; N = C_;
    bx = (rel & 15) * 64; by = (rel >> 4) * 64;
  }
  for (int idx = tid; idx < 4096; idx += 256) {
    int r = idx >> 6, c = idx & 63;
    tile[r][c] = f2bf(src[(size_t)(by + r) * N + bx + c]);
  }
  __syncthreads();
  for (int idx = tid; idx < 4096; idx += 256) {
    int r = idx >> 6, c = idx & 63;
    dst[(size_t)(bx + r) * C_ + by + c] = tile[c][r];
  }
}

// -------- GEMM 1: qkv = X(4096x1024)bf16 @ WT(3072x1024)bf16, RoPE epilogue.
// 128x128 tile, BK=64, dbuf chunk-XOR-swizzled LDS (r5-proven, conflicts=0). FROZEN
// — 4 structural rewrites (8-phase, depth-2 vmcnt, B-direct, 192-tile) all lost.
// q pre-scaled by 0.125*log2e: attn computes P = exp2(S) directly. --------
__global__ __launch_bounds__(256) void gemm_qkv_rope(const u16* __restrict__ X,
                                                     const u16* __restrict__ WT,
                                                     u16* __restrict__ qb,
                                                     u16* __restrict__ kb,
                                                     u16* __restrict__ vtb) {
  const int K = C_;
  __shared__ __align__(16) u16 As[2][128 * 64];  // 32 KB
  __shared__ __align__(16) u16 Bs[2][128 * 64];  // 32 KB
  int tid = threadIdx.x;
  int lane = tid & 63, wave = tid >> 6;
  int quad = lane >> 4, lr = lane & 15;
  int m0 = blockIdx.y * 128, n0 = blockIdx.x * 128;
  int wrow = (wave >> 1) * 64, wcol = (wave & 1) * 64;
  int r0 = wave * 32;  // this wave's staging row base (32 rows per wave)
  int srow = lane >> 3;
  int schunk = (lane & 7) ^ srow;  // pre-swizzled global source chunk

  // read-side swizzled chunk offsets (u16 units): logical chunk (ks*4+quad) ^ (row&7)
  int koff0 = ((quad ^ (lr & 7)) << 3);
  int koff1 = (((4 | quad) ^ (lr & 7)) << 3);

  f32x4 zero = {0.f, 0.f, 0.f, 0.f};
  f32x4 acc[4][4];
#pragma unroll
  for (int i = 0; i < 4; i++)
#pragma unroll
    for (int j = 0; j < 4; j++) acc[i][j] = zero;

  const u16* ga = X + (size_t)(m0 + r0 + srow) * K + schunk * 8;
  const u16* gb = WT + (size_t)(n0 + r0 + srow) * K + schunk * 8;

  // prologue: stage tile 0 (8 loads/thread: 4 A-rowgroups + 4 B-rowgroups)
#pragma unroll
  for (int l = 0; l < 4; l++) {
    load_lds16(ga + (size_t)(l * 8) * K, &As[0][(r0 + l * 8) * 64]);
    load_lds16(gb + (size_t)(l * 8) * K, &Bs[0][(r0 + l * 8) * 64]);
  }

  int buf = 0;
  for (int k0 = 0; k0 < K; k0 += 64) {
    __syncthreads();  // drains tile-k0 loads (issued one compute phase ago)
    if (k0 + 64 < K) {
#pragma unroll
      for (int l = 0; l < 4; l++) {
        load_lds16(ga + (size_t)(l * 8) * K + k0 + 64, &As[buf ^ 1][(r0 + l * 8) * 64]);
        load_lds16(gb + (size_t)(l * 8) * K + k0 + 64, &Bs[buf ^ 1][(r0 + l * 8) * 64]);
      }
    }
    bfrag8 af[4][2], bf[4][2];
#pragma unroll
    for (int i = 0; i < 4; i++) {
      const u16* ar = &As[buf][(wrow + i * 16 + lr) * 64];
      af[i][0] = *(const bfrag8*)(ar + koff0);
      af[i][1] = *(const bfrag8*)(ar + koff1);
    }
#pragma unroll
    for (int j = 0; j < 4; j++) {
      const u16* br = &Bs[buf][(wcol + j * 16 + lr) * 64];
      bf[j][0] = *(const bfrag8*)(br + koff0);
      bf[j][1] = *(const bfrag8*)(br + koff1);
    }
#pragma unroll
    for (int i = 0; i < 4; i++)
#pragma unroll
      for (int j = 0; j < 4; j++) {
        acc[i][j] = MFMA_BF16(af[i][0], bf[j][0], acc[i][j]);
        acc[i][j] = MFMA_BF16(af[i][1], bf[j][1], acc[i][j]);
      }
    buf ^= 1;
  }

  int colbase = n0 + wcol;
  int which = colbase >> 10;  // 0=q 1=k 2=v
  int h = (colbase & 1023) >> 6;
  if (which < 2) {
    u16* dst = which == 0 ? qb : kb;
    // q pre-scaled by 1/8 * log2(e): attn computes P = exp2(S) directly
    float sc0 = (which == 0) ? 0.18033688011112042f : 1.0f;
    float fr0 = __expf(-0.28782313662425574f * (float)lr);        // ln(10000)/32
    float fr1 = __expf(-0.28782313662425574f * (float)(16 + lr));
#pragma unroll
    for (int i = 0; i < 4; i++) {
#pragma unroll
      for (int r = 0; r < 4; r++) {
        int m = m0 + wrow + i * 16 + quad * 4 + r;
        int b = m >> 11, tt = m & 2047;
        size_t base = ((size_t)(b * H_ + h) * T_ + tt) * D_;
        float sn, cs;
        __sincosf((float)tt * fr0, &sn, &cs);
        dst[base + lr] = f2bf((acc[i][0][r] * cs - acc[i][2][r] * sn) * sc0);
        dst[base + lr + 32] = f2bf((acc[i][0][r] * sn + acc[i][2][r] * cs) * sc0);
        __sincosf((float)tt * fr1, &sn, &cs);
        dst[base + 16 + lr] = f2bf((acc[i][1][r] * cs - acc[i][3][r] * sn) * sc0);
        dst[base + 48 + lr] = f2bf((acc[i][1][r] * sn + acc[i][3][r] * cs) * sc0);
      }
    }
  } else {
    // V: write transposed [bh][d][t]; lane holds 4 consecutive t per (i,j) -> 8B store
#pragma unroll
    for (int i = 0; i < 4; i++) {
      int mb = m0 + wrow + i * 16 + quad * 4;  // 4 consecutive t from here (same b)
      int b = mb >> 11, tt = mb & 2047;
      u16* vb = vtb + ((size_t)(b * H_ + h) * D_) * T_ + tt;
#pragma unroll
      for (int j = 0; j < 4; j++) {
        union { uint2 v; u16 hh[4]; } pk;
#pragma unroll
        for (int r = 0; r < 4; r++) pk.hh[r] = f2bf(acc[i][j][r]);
        *(uint2*)(vb + (size_t)(j * 16 + lr) * T_) = pk.v;
      }
    }
  }
}

// -------- attention: causal, S^T formulation, q-tile 128 (8 waves, 512 thr,
// 16 q-rows/wave). kv staging tile 128 (2 subtiles/barrier), balanced dispatch
// pairing (r15). r16: Pst halved to [8][16*32] (8 KB) — Pst is per-wave private
// (no barrier involvement), and PV's two k-steps consume disjoint 32-t halves of P,
// so softmax+PV run in two halves sharing one slice. Total LDS 80->72 KB: at 80 KB,
// 2x80 = exactly the 160 KiB pool (exact-fill may be disallowed -> 1 block/CU, zero
// inter-block TLP, and r15's pairing provably null — matches observation). 72 KB
// GUARANTEES 2 blocks/CU. Sync structure unchanged. ----
__global__ __launch_bounds__(512) void attn_k(const u16* __restrict__ qb,
                                              const u16* __restrict__ kb,
                                              const u16* __restrict__ vtb,
                                              u16* __restrict__ ob) {
  __shared__ __align__(16) u16 Ks[2][128 * 64];  // [t][chunk^(t&7)]   16 KB each
  __shared__ __align__(16) u16 Vt[2][64 * 128];  // [d][chunk16^(d&7)] 16 KB each
  __shared__ __align__(16) u16 Pst[8][16 * 32];  // per-wave P half, chunk-XOR swizzled
  int tid = threadIdx.x;
  int lane = tid & 63, wave = tid >> 6;
  int quad = lane >> 4, lr = lane & 15;
  int i = blockIdx.x;
  // balanced pairing: i<256 -> bq 15..8 (heavy, dispatched first);
  // i>=256 -> bq 0..7 so that blocks i and i+256 sum to constant work.
  int bq = (i < 256) ? (15 - (i >> 5)) : ((i >> 5) - 8);
  int bh = i & 31;
  int b = bh >> 4, h2 = bh & 15;
  const u16* Q = qb + (size_t)bh * T_ * D_;
  const u16* Kp = kb + (size_t)bh * T_ * D_;
  const u16* Vp = vtb + (size_t)bh * D_ * T_;
  int qr0 = bq * 128 + wave * 16;  // this wave's q-row base

  // K staging: 16 rows/wave, 2 calls of 8 rows; 8 lanes/row, chunk pre-swizzled
  int rK = lane >> 3;
  int cK = ((lane & 7) ^ rK) * 8;
  const u16* gk0 = Kp + (size_t)(wave * 16 + rK) * D_ + cK;
  const u16* gk1 = gk0 + (size_t)8 * D_;
  // V staging: 8 d-rows/wave (256B each), 2 calls of 4 rows; 16 lanes/row
  int rV = lane >> 4;
  int cV = (lane & 15) ^ rV;  // call0 source chunk16; call1 = cV^4 (row&7 += 4)
  const u16* gv0 = Vp + (size_t)(wave * 8 + rV) * T_ + cV * 8;
  const u16* gv1 = Vp + (size_t)(wave * 8 + 4 + rV) * T_ + (cV ^ 4) * 8;

  // read-side swizzled chunk offsets (u16 units), constant per lane
  int koff0 = ((quad ^ (lr & 7)) << 3);
  int koff1 = (((4 | quad) ^ (lr & 7)) << 3);
  int lsw = lr & 7;
  int lsw4 = lr & 3;  // Pst swizzle key (4-chunk rows)

  // Q fragment as MFMA B-operand: B[n=q][k=d] (from global, unswizzled)
  bfrag8 qf[2];
#pragma unroll
  for (int ks = 0; ks < 2; ks++)
    qf[ks] = *(const bfrag8*)(Q + (size_t)(qr0 + lr) * D_ + ks * 32 + quad * 8);

  f32x4 zero = {0.f, 0.f, 0.f, 0.f};
  f32x4 o[4];
#pragma unroll
  for (int nn = 0; nn < 4; nn++) o[nn] = zero;
  float ps0 = 0.f, ps1 = 0.f, ps2 = 0.f, ps3 = 0.f;

  int nkt = bq + 1;                  // kv 128-tiles
  int wlast = 2 * bq + (wave >> 2);  // this wave's causal last SUBTILE (64-granule)
  int qloc = (wave & 3) * 16 + lr;   // q-pos within last subtile

  // prologue: stage kv-tile 0 (4 calls/thread)
  load_lds16(gk0, &Ks[0][(wave * 16) * 64]);
  load_lds16(gk1, &Ks[0][(wave * 16 + 8) * 64]);
  load_lds16(gv0, &Vt[0][(wave * 8) * 128]);
  load_lds16(gv1, &Vt[0][(wave * 8 + 4) * 128]);

  int buf = 0;
  for (int kt = 0; kt < nkt; kt++) {
    __syncthreads();  // drains tile-kt loads (issued one compute phase ago)
    if (kt + 1 < nkt) {
      int tb = (kt + 1) * 128;
      load_lds16(gk0 + (size_t)tb * D_, &Ks[buf ^ 1][(wave * 16) * 64]);
      load_lds16(gk1 + (size_t)tb * D_, &Ks[buf ^ 1][(wave * 16 + 8) * 64]);
      load_lds16(gv0 + tb, &Vt[buf ^ 1][(wave * 8) * 128]);
      load_lds16(gv1 + tb, &Vt[buf ^ 1][(wave * 8 + 4) * 128]);
    }
    const u16* ks_ = Ks[buf];
    const u16* vt_ = Vt[buf];
#pragma unroll
    for (int h = 0; h < 2; h++) {
      int st = 2 * kt + h;
      if (st <= wlast) {  // wave-uniform
        // S^T = K Q^T : 64 kv-rows x 16 q-cols (A=K-frag swizzled, B=Q-frag)
        f32x4 s[4];
#pragma unroll
        for (int j = 0; j < 4; j++) s[j] = zero;
#pragma unroll
        for (int j = 0; j < 4; j++) {
          const u16* kr = &ks_[(h * 64 + j * 16 + lr) * 64];
          bfrag8 kf0 = *(const bfrag8*)(kr + koff0);
          bfrag8 kf1 = *(const bfrag8*)(kr + koff1);
          s[j] = MFMA_BF16(kf0, qf[0], s[j]);
          s[j] = MFMA_BF16(kf1, qf[1], s[j]);
        }

        bool edge = (st == wlast);  // wave-uniform
        // two halves sharing one Pst slice: ha=0 -> j{0,1}, PV ks=0;
        // ha=1 -> j{2,3}, PV ks=1. Per-wave DS ops are in-order -> no sync needed.
#pragma unroll
        for (int ha = 0; ha < 2; ha++) {
#pragma unroll
          for (int jj = 0; jj < 2; jj++) {
            int j = ha * 2 + jj;
            float p[4];
#pragma unroll
            for (int r = 0; r < 4; r++) {
              float e = exp2_fast(s[j][r]);
              if (edge) {
                int kvloc = j * 16 + quad * 4 + r;
                e = (kvloc <= qloc) ? e : 0.f;
              }
              p[r] = e;
            }
            ps0 += p[0];
            ps1 += p[1];
            ps2 += p[2];
            ps3 += p[3];
            u32 u0 = __builtin_bit_cast(u32, p[0]) + 0x8000u;
            u32 u1 = __builtin_bit_cast(u32, p[1]) + 0x8000u;
            u32 u2 = __builtin_bit_cast(u32, p[2]) + 0x8000u;
            u32 u3 = __builtin_bit_cast(u32, p[3]) + 0x8000u;
            uint2 pk;
            pk.x = (u0 >> 16) | (u1 & 0xffff0000u);
            pk.y = (u2 >> 16) | (u3 & 0xffff0000u);
            // t-local = jj*16 + quad*4 + r; 16B-chunk (2jj + quad>>1) ^ lsw4
            *(uint2*)&Pst[wave][lr * 32 + (((2 * jj + (quad >> 1)) ^ lsw4) << 3) +
                                ((quad & 1) << 2)] = pk;
          }
          // PV k-step ha: pf = P[q=lr][t-local = quad*8..+8] (chunk quad ^ lsw4)
          bfrag8 pf = *(const bfrag8*)&Pst[wave][lr * 32 + ((quad ^ lsw4) << 3)];
#pragma unroll
          for (int nn = 0; nn < 4; nn++) {
            int vko = ((8 * h + 4 * ha + quad) ^ lsw) << 3;
            bfrag8 vf = *(const bfrag8*)&vt_[(nn * 16 + lr) * 128 + vko];
            o[nn] = MFMA_BF16(pf, vf, o[nn]);
          }
        }
      }
    }
    buf ^= 1;
  }

  // total row-sum: reduce over the 4 quads
  float l = (ps0 + ps1) + (ps2 + ps3);
  l += __shfl_xor(l, 16, 64);
  l += __shfl_xor(l, 32, 64);
  float linv = 1.0f / l;

#pragma unroll
  for (int r = 0; r < 4; r++) {
    float lrec = __shfl(linv, quad * 4 + r, 64);
    int row = qr0 + quad * 4 + r;
#pragma unroll
    for (int nn = 0; nn < 4; nn++)
      ob[(size_t)(b * T_ + row) * C_ + h2 * 64 + nn * 16 + lr] = f2bf(o[nn][r] * lrec);
  }
}

// -------- GEMM 2: out(f32) = A(4096x1024)bf16 @ WT(1024x1024)bf16 + bias(f32).
// 64x128 tile (grid 512), BK=64 + chunk-XOR swizzle (r7 exact, FROZEN). --------
__global__ __launch_bounds__(256) void gemm_proj(const u16* __restrict__ A,
                                                 const u16* __restrict__ WT,
                                                 const float* __restrict__ bias,
                                                 float* __restrict__ out) {
  const int K = C_;
  __shared__ __align__(16) u16 As[2][64 * 64];   // 16 KB
  __shared__ __align__(16) u16 Bs[2][128 * 64];  // 32 KB
  int tid = threadIdx.x;
  int lane = tid & 63, wave = tid >> 6;
  int quad = lane >> 4, lr = lane & 15;
  int m0 = blockIdx.y * 64, n0 = blockIdx.x * 128;
  int wcol = wave * 32;
  int srow = lane >> 3;
  int schunk = (lane & 7) ^ srow;  // pre-swizzled global source chunk

  int koff0 = ((quad ^ (lr & 7)) << 3);
  int koff1 = (((4 | quad) ^ (lr & 7)) << 3);

  f32x4 zero = {0.f, 0.f, 0.f, 0.f};
  f32x4 acc[4][2];
#pragma unroll
  for (int i = 0; i < 4; i++)
#pragma unroll
    for (int j = 0; j < 2; j++) acc[i][j] = zero;

  const u16* ga = A + (size_t)(m0 + wave * 16 + srow) * K + schunk * 8;
  const u16* gb = WT + (size_t)(n0 + wave * 32 + srow) * K + schunk * 8;

  // prologue: A rows wave*16 + {0,8}; B rows wave*32 + {0,8,16,24}
  load_lds16(ga, &As[0][(wave * 16) * 64]);
  load_lds16(ga + (size_t)8 * K, &As[0][(wave * 16 + 8) * 64]);
#pragma unroll
  for (int l = 0; l < 4; l++)
    load_lds16(gb + (size_t)(l * 8) * K, &Bs[0][(wave * 32 + l * 8) * 64]);

  int buf = 0;
  for (int k0 = 0; k0 < K; k0 += 64) {
    __syncthreads();
    if (k0 + 64 < K) {
      load_lds16(ga + k0 + 64, &As[buf ^ 1][(wave * 16) * 64]);
      load_lds16(ga + (size_t)8 * K + k0 + 64, &As[buf ^ 1][(wave * 16 + 8) * 64]);
#pragma unroll
      for (int l = 0; l < 4; l++)
        load_lds16(gb + (size_t)(l * 8) * K + k0 + 64, &Bs[buf ^ 1][(wave * 32 + l * 8) * 64]);
    }
    bfrag8 af[4][2], bf[2][2];
#pragma unroll
    for (int i = 0; i < 4; i++) {
      const u16* ar = &As[buf][(i * 16 + lr) * 64];
      af[i][0] = *(const bfrag8*)(ar + koff0);
      af[i][1] = *(const bfrag8*)(ar + koff1);
    }
#pragma unroll
    for (int j = 0; j < 2; j++) {
      const u16* br = &Bs[buf][(wcol + j * 16 + lr) * 64];
      bf[j][0] = *(const bfrag8*)(br + koff0);
      bf[j][1] = *(const bfrag8*)(br + koff1);
    }
#pragma unroll
    for (int i = 0; i < 4; i++)
#pragma unroll
      for (int j = 0; j < 2; j++) {
        acc[i][j] = MFMA_BF16(af[i][0], bf[j][0], acc[i][j]);
        acc[i][j] = MFMA_BF16(af[i][1], bf[j][1], acc[i][j]);
      }
    buf ^= 1;
  }

#pragma unroll
  for (int i = 0; i < 4; i++)
#pragma unroll
    for (int r = 0; r < 4; r++) {
      int m = m0 + i * 16 + quad * 4 + r;
#pragma unroll
      for (int j = 0; j < 2; j++) {
        int n = n0 + wcol + j * 16 + lr;
        out[(size_t)m * C_ + n] = acc[i][j][r] + bias[n];
      }
    }
}

extern "C" void kernel_launch(void* const* d_in, const int* in_sizes, int n_in,
                              void* d_out, int out_size, void* d_ws, size_t ws_size,
                              hipStream_t stream) {
  const float* x = (const float*)d_in[0];       // [4096,1024] f32
  const float* w_qkv = (const float*)d_in[1];   // [1024,3072] f32
  const float* w_proj = (const float*)d_in[2];  // [1024,1024] f32
  const float* b_proj = (const float*)d_in[3];  // [1024] f32

  char* w = (char*)d_ws;
  u16* xb = (u16*)(w + 256);                 // 4096*1024 bf16 (A for gemm_qkv)
  u16* regA = xb + (size_t)4096 * 1024;      // max(wqkvT, abuf)
  u16* wqkvT = regA;                         // 3072*1024 (dead after gemm_qkv)
  u16* abuf = regA;                          // 4096*1024 (written by attn)
  u16* wprojT = regA + (size_t)4096 * 1024;  // 1024*1024
  u16* qbuf = wprojT + (size_t)1024 * 1024;
  u16* kbuf = qbuf + (size_t)B_ * H_ * T_ * D_;
  u16* vtb = kbuf + (size_t)B_ * H_ * T_ * D_;  // V^T [bh][d][t] (written by gemm_qkv)

  prep<<<3072, 256, 0, stream>>>(x, xb, w_qkv, wqkvT, w_proj, wprojT);
  gemm_qkv_rope<<<dim3(NQKV_ / 128, (B_ * T_) / 128), 256, 0, stream>>>(xb, wqkvT, qbuf, kbuf, vtb);
  attn_k<<<512, 512, 0, stream>>>(qbuf, kbuf, vtb, abuf);
  gemm_proj<<<dim3(C_ / 128, (B_ * T_) / 64), 256, 0, stream>>>(abuf, wprojT, b_proj, (float*)d_out);
}